// Round 1
// baseline (96.502 us; speedup 1.0000x reference)
//
#include <hip/hip_runtime.h>
#include <hip/hip_fp16.h>

// WordGraphNet fp32. Round 14: column-split gather working sets.
// Wh1/Wh2 are stored as TWO 3.2MB half-matrices (cols 0-31, cols 32-63,
// row stride 32 halves). Aggregation (agg1 + agg2) runs two sequential
// column passes so the instantaneous random-gather working set fits the
// 4MiB per-XCD L2 (6.4MB did not -> capacity thrash to L3). Edge-list
// re-walk is free: agg1 re-reads lsort from LDS; agg2 re-shuffles its
// register-preloaded payloads. GEMMs write the split layout directly.
// Pipeline: memset | fill+gemm1 | sort+agg1+gemm2 | agg2.  (~60us of total
// is harness ws-poison/restore, visible as the only top-5 entries.)

#define N_NODES 50000
#define N_EDGES 1200000
#define IN_SIZE 128
#define HID 64
#define NEG_SLOPE 0.01f
#define NBC 196           // coarse buckets: ceil(50000/256)
#define SLOTC 6656        // slots/bucket (mean 6144, sigma 78 -> +6.5 sigma)
#define FILL_EPB 8192
#define FILL_BLOCKS ((N_EDGES + FILL_EPB - 1) / FILL_EPB)   // 147
#define GEMM_BLOCKS ((N_NODES + 255) / 256)                 // 196
#define LHALF 4096        // lsort capacity per half-bucket (mean 3072, +13sg)
#define RS2 (HID + 8)     // padded LDS row stride (72 halves = 144B)
#define HHALF 32          // column-half width
#define WSPLIT ((size_t)N_NODES * HHALF)   // element offset of col-half 1

typedef _Float16 half8 __attribute__((ext_vector_type(8)));
typedef _Float16 half4 __attribute__((ext_vector_type(4)));
typedef float floatx4 __attribute__((ext_vector_type(4)));

// ---------------- MFMA GEMM body (1024 thr, 256 rows/blk), fp32 A -----------
// Output is written COLUMN-SPLIT: cols [0,32) at out, cols [32,64) at
// out + WSPLIT, row stride HHALF.
template <int K>
__device__ __forceinline__ void gemm_body(int blk,
                                          const float* __restrict__ A,
                                          const float* __restrict__ W,
                                          const float* __restrict__ b,
                                          _Float16* __restrict__ out,
                                          _Float16* wthi, _Float16* wtlo) {
    constexpr int RS = K + 8;
    const int tid = threadIdx.x;
    for (int i = tid; i < 64 * K; i += 1024) {
        int n = i / K, k = i % K;
        float wv = W[k * 64 + n];
        _Float16 hi = (_Float16)wv;
        wthi[n * RS + k] = hi;
        wtlo[n * RS + k] = (_Float16)(wv - (float)hi);
    }
    __syncthreads();

    const int lane = tid & 63;
    const int wid = tid >> 6;
    const int q = lane >> 4, c = lane & 15;

    int arow = blk * 256 + wid * 16 + c;
    int lrow = min(arow, N_NODES - 1);
    const float* ap = A + (size_t)lrow * K + q * 8;

    floatx4 acc0 = {b[c],      b[c],      b[c],      b[c]};
    floatx4 acc1 = {b[c + 16], b[c + 16], b[c + 16], b[c + 16]};
    floatx4 acc2 = {b[c + 32], b[c + 32], b[c + 32], b[c + 32]};
    floatx4 acc3 = {b[c + 48], b[c + 48], b[c + 48], b[c + 48]};

#pragma unroll
    for (int ks = 0; ks < K / 32; ++ks) {
        float4 f0 = ((const float4*)(ap + ks * 32))[0];
        float4 f1 = ((const float4*)(ap + ks * 32))[1];
        float fv[8] = {f0.x, f0.y, f0.z, f0.w, f1.x, f1.y, f1.z, f1.w};
        half8 ahi, alo;
#pragma unroll
        for (int j = 0; j < 8; ++j) {
            _Float16 h = (_Float16)fv[j];
            ahi[j] = h;
            alo[j] = (_Float16)(fv[j] - (float)h);
        }
        const int kb = ks * 32 + q * 8;
        half8 bh0 = *(const half8*)&wthi[(c     ) * RS + kb];
        half8 bl0 = *(const half8*)&wtlo[(c     ) * RS + kb];
        half8 bh1 = *(const half8*)&wthi[(c + 16) * RS + kb];
        half8 bl1 = *(const half8*)&wtlo[(c + 16) * RS + kb];
        half8 bh2 = *(const half8*)&wthi[(c + 32) * RS + kb];
        half8 bl2 = *(const half8*)&wtlo[(c + 32) * RS + kb];
        half8 bh3 = *(const half8*)&wthi[(c + 48) * RS + kb];
        half8 bl3 = *(const half8*)&wtlo[(c + 48) * RS + kb];
        acc0 = __builtin_amdgcn_mfma_f32_16x16x32_f16(ahi, bh0, acc0, 0, 0, 0);
        acc0 = __builtin_amdgcn_mfma_f32_16x16x32_f16(ahi, bl0, acc0, 0, 0, 0);
        acc0 = __builtin_amdgcn_mfma_f32_16x16x32_f16(alo, bh0, acc0, 0, 0, 0);
        acc1 = __builtin_amdgcn_mfma_f32_16x16x32_f16(ahi, bh1, acc1, 0, 0, 0);
        acc1 = __builtin_amdgcn_mfma_f32_16x16x32_f16(ahi, bl1, acc1, 0, 0, 0);
        acc1 = __builtin_amdgcn_mfma_f32_16x16x32_f16(alo, bh1, acc1, 0, 0, 0);
        acc2 = __builtin_amdgcn_mfma_f32_16x16x32_f16(ahi, bh2, acc2, 0, 0, 0);
        acc2 = __builtin_amdgcn_mfma_f32_16x16x32_f16(ahi, bl2, acc2, 0, 0, 0);
        acc2 = __builtin_amdgcn_mfma_f32_16x16x32_f16(alo, bh2, acc2, 0, 0, 0);
        acc3 = __builtin_amdgcn_mfma_f32_16x16x32_f16(ahi, bh3, acc3, 0, 0, 0);
        acc3 = __builtin_amdgcn_mfma_f32_16x16x32_f16(ahi, bl3, acc3, 0, 0, 0);
        acc3 = __builtin_amdgcn_mfma_f32_16x16x32_f16(alo, bh3, acc3, 0, 0, 0);
    }

    int rowb = blk * 256 + wid * 16 + q * 4;
#pragma unroll
    for (int r = 0; r < 4; ++r) {
        if (rowb + r < N_NODES) {
            // col-split store: acc0/acc1 -> cols c/c+16 of half 0,
            //                  acc2/acc3 -> cols c/c+16 of half 1.
            _Float16* opA = out + (size_t)(rowb + r) * HHALF + c;
            opA[0]  = (_Float16)acc0[r];
            opA[16] = (_Float16)acc1[r];
            _Float16* opB = out + WSPLIT + (size_t)(rowb + r) * HHALF + c;
            opB[0]  = (_Float16)acc2[r];
            opB[16] = (_Float16)acc3[r];
        }
    }
}

// ---------------- fill body v4: 8192 edges, 196 coarse bins, 1024 thr -------
__device__ __forceinline__ void fill_body(int blk,
                                          const int* __restrict__ src,
                                          const int* __restrict__ dst,
                                          const float* __restrict__ ew,
                                          int* __restrict__ gcur,
                                          int2* __restrict__ epack,
                                          int* lhist, int* lbase) {
    const int tid = threadIdx.x;
    const int e0 = blk * FILL_EPB;
    if (tid < NBC) lhist[tid] = 0;

    const int g0 = e0 + 4 * tid, g1 = g0 + 4096;
    const bool a0 = g0 < N_EDGES, a1 = g1 < N_EDGES;
    int4 d0 = {0,0,0,0}, d1 = {0,0,0,0}, s0 = {0,0,0,0}, s1 = {0,0,0,0};
    float4 w0 = {0,0,0,0}, w1 = {0,0,0,0};
    if (a0) { d0 = *(const int4*)(dst + g0); s0 = *(const int4*)(src + g0);
              w0 = *(const float4*)(ew + g0); }
    if (a1) { d1 = *(const int4*)(dst + g1); s1 = *(const int4*)(src + g1);
              w1 = *(const float4*)(ew + g1); }
    __syncthreads();

    if (a0) { atomicAdd(&lhist[d0.x >> 8], 1); atomicAdd(&lhist[d0.y >> 8], 1);
              atomicAdd(&lhist[d0.z >> 8], 1); atomicAdd(&lhist[d0.w >> 8], 1); }
    if (a1) { atomicAdd(&lhist[d1.x >> 8], 1); atomicAdd(&lhist[d1.y >> 8], 1);
              atomicAdd(&lhist[d1.z >> 8], 1); atomicAdd(&lhist[d1.w >> 8], 1); }
    __syncthreads();

    if (tid < NBC) {
        int c = lhist[tid];
        lbase[tid] = tid * SLOTC + (c ? atomicAdd(&gcur[tid], c) : 0);
        lhist[tid] = 0;                      // reuse as local cursor
    }
    __syncthreads();

    const int dd0[4] = {d0.x, d0.y, d0.z, d0.w};
    const int ss0[4] = {s0.x, s0.y, s0.z, s0.w};
    const float ww0[4] = {w0.x, w0.y, w0.z, w0.w};
    const int dd1[4] = {d1.x, d1.y, d1.z, d1.w};
    const int ss1[4] = {s1.x, s1.y, s1.z, s1.w};
    const float ww1[4] = {w1.x, w1.y, w1.z, w1.w};
    if (a0) {
#pragma unroll
        for (int j = 0; j < 4; ++j) {
            int d = dd0[j], b = d >> 8;
            int idx = lbase[b] + atomicAdd(&lhist[b], 1);
            if (idx < (b + 1) * SLOTC)       // 6.5-sigma guard, never taken
                epack[idx] = make_int2(ss0[j] | ((d & 255) << 16),
                                       __float_as_int(ww0[j]));
        }
    }
    if (a1) {
#pragma unroll
        for (int j = 0; j < 4; ++j) {
            int d = dd1[j], b = d >> 8;
            int idx = lbase[b] + atomicAdd(&lhist[b], 1);
            if (idx < (b + 1) * SLOTC)
                epack[idx] = make_int2(ss1[j] | ((d & 255) << 16),
                                       __float_as_int(ww1[j]));
        }
    }
}

// ---------------- fused dispatch: fill (0..146) + gemm1 (147..342) ----------
__global__ __launch_bounds__(1024) void fill_gemm1(const int* __restrict__ src,
                                                   const int* __restrict__ dst,
                                                   const float* __restrict__ ew,
                                                   int* __restrict__ gcur,
                                                   int2* __restrict__ epack,
                                                   const float* __restrict__ x,
                                                   const float* __restrict__ W1,
                                                   const float* __restrict__ b1,
                                                   _Float16* __restrict__ outA) {
    __shared__ union SU {
        struct { int lhist[NBC]; int lbase[NBC]; } f;
        struct { _Float16 hi[64 * (IN_SIZE + 8)];
                 _Float16 lo[64 * (IN_SIZE + 8)]; } g;
    } u;
    if (blockIdx.x < FILL_BLOCKS)
        fill_body(blockIdx.x, src, dst, ew, gcur, epack, u.f.lhist, u.f.lbase);
    else
        gemm_body<IN_SIZE>(blockIdx.x - FILL_BLOCKS, x, W1, b1, outA,
                           u.g.hi, u.g.lo);
}

// ---------------- fused sort + agg1 + gemm2 (block = half-bucket) -----------
// Phase S: hist -> scan (off written for agg2) -> scatter my half to lsort
//          -> stream lsort to esort (for agg2).
// Phase A: group-per-node (16 waves x 8 groups = 128 nodes exactly); TWO
//          sequential column passes (Wh1 half A then half B, 3.2MB each ->
//          fits per-XCD L2); per edge: 8-lane-broadcast ds_read of lsort +
//          8B half4 gather + 4 fma.
// Phase G: Wh2[128,64] = h1_tile @ W2 + b2 (fp16 A exact, hi/lo W2),
//          written column-split.
__global__ __launch_bounds__(1024) void sort_agg1_gemm2(
        const int* __restrict__ gcur, const int2* __restrict__ epack,
        const _Float16* __restrict__ Wh1,
        const float* __restrict__ W2, const float* __restrict__ b2,
        unsigned int* __restrict__ esort, int* __restrict__ off,
        _Float16* __restrict__ outB) {
    __shared__ unsigned int lsort[LHALF];     // 16 KB
    __shared__ int cnt[256];
    __shared__ int start[256];
    __shared__ int wsum[4];
    __shared__ int s_h128;
    __shared__ _Float16 w2hi[64 * RS2];       // 9.2 KB
    __shared__ _Float16 w2lo[64 * RS2];       // 9.2 KB
    __shared__ _Float16 hs[128 * RS2];        // 18 KB h1 tile
    const int tid = threadIdx.x;
    const int bkt = blockIdx.x >> 1;
    const int half = blockIdx.x & 1;
    const int beg = bkt * SLOTC;
    const int n = min(gcur[bkt], SLOTC);

    // stage W2 transposed hi/lo (overlaps hist)
    for (int i = tid; i < 64 * HID; i += 1024) {
        int nn = i >> 6, k = i & 63;
        float wv = W2[k * 64 + nn];
        _Float16 hi = (_Float16)wv;
        w2hi[nn * RS2 + k] = hi;
        w2lo[nn * RS2 + k] = (_Float16)(wv - (float)hi);
    }
    if (tid < 256) cnt[tid] = 0;
    __syncthreads();
    for (int e = tid; e < n; e += 1024)       // full 256-bin hist
        atomicAdd(&cnt[(epack[beg + e].x >> 16) & 255], 1);
    __syncthreads();
    int orig = 0, incl = 0;
    if (tid < 256) {
        orig = cnt[tid];
        int v = orig;
        for (int o = 1; o < 64; o <<= 1) {
            int t = __shfl_up(v, o);
            if ((tid & 63) >= o) v += t;
        }
        if ((tid & 63) == 63) wsum[tid >> 6] = v;
        incl = v;
    }
    __syncthreads();
    if (tid < 256) {
        int w = tid >> 6;
        for (int k = 0; k < w; ++k) incl += wsum[k];
        int excl = incl - orig;
        start[tid] = excl;
        if (tid == 128) s_h128 = excl;
        if ((tid >> 7) == half)               // this block's half of off[]
            off[bkt * 257 + tid] = beg + excl;
        if (half == 1 && tid == 255)
            off[bkt * 257 + 256] = beg + incl;
        cnt[tid] = 0;                          // reuse as cursor
    }
    __syncthreads();
    const int halfbase = half ? s_h128 : 0;
    const int nhalf = min(half ? (n - s_h128) : s_h128, LHALF);
    for (int e = tid; e < n; e += 1024) {
        int2 pk = epack[beg + e];
        int d8 = (pk.x >> 16) & 255;
        if ((d8 >> 7) != half) continue;
        int pos = atomicAdd(&cnt[d8], 1);
        int idx = start[d8] + pos - halfbase;
        unsigned short hw = __half_as_ushort(__float2half(__int_as_float(pk.y)));
        if (idx < LHALF)
            lsort[idx] = (unsigned int)(pk.x & 0xffff) | ((unsigned int)hw << 16);
    }
    __syncthreads();
    // stream to esort for agg2 (coalesced)
    for (int i = tid; i < nhalf; i += 1024)
        esort[beg + halfbase + i] = lsort[i];

    // Phase A: aggregate from LDS, two sequential column passes.
    {
        const int lane = tid & 63;
        const int g = lane >> 3, p = lane & 7;
        const int nl = (tid >> 6) * 8 + g;    // 0..127
        const int d8 = half * 128 + nl;
        const int lbeg = start[d8] - halfbase;
        const int deg = cnt[d8];              // cursor == bin count
        const int lend = min(lbeg + deg, LHALF);
        const float inv = 1.0f / fmaxf((float)deg, 1.0f);
#pragma unroll
        for (int h = 0; h < 2; ++h) {
            const _Float16* Wp = Wh1 + (size_t)h * WSPLIT;
            float acc[4] = {0, 0, 0, 0};
            for (int e = lbeg; e < lend; ++e) {
                const unsigned int pe = lsort[e]; // 8-lane broadcast read
                const float w =
                    __half2float(__ushort_as_half((unsigned short)(pe >> 16)));
                half4 row = *(const half4*)(Wp + (size_t)(pe & 0xffff) * HHALF
                                            + p * 4);
#pragma unroll
                for (int j = 0; j < 4; ++j)
                    acc[j] = fmaf((float)row[j], w, acc[j]);
            }
            half4 hv;
#pragma unroll
            for (int j = 0; j < 4; ++j) {
                float t = acc[j] * inv;
                t = t >= 0.0f ? t : NEG_SLOPE * t;   // leaky relu
                hv[j] = (_Float16)t;
            }
            *(half4*)&hs[nl * RS2 + h * HHALF + p * 4] = hv;
        }
    }
    __syncthreads();

    // Phase G: gemm2. wave w: row-tile r = w>>1 (16 rows), col half ch = w&1.
    {
        const int lane = tid & 63, wid = tid >> 6;
        const int q = lane >> 4, c = lane & 15;
        const int r = wid >> 1, ch = wid & 1;
        floatx4 acc0 = {b2[ch * 32 + c], b2[ch * 32 + c],
                        b2[ch * 32 + c], b2[ch * 32 + c]};
        floatx4 acc1 = {b2[ch * 32 + 16 + c], b2[ch * 32 + 16 + c],
                        b2[ch * 32 + 16 + c], b2[ch * 32 + 16 + c]};
#pragma unroll
        for (int ks = 0; ks < 2; ++ks) {
            const int kb = ks * 32 + q * 8;
            half8 a = *(const half8*)&hs[(r * 16 + c) * RS2 + kb];
            half8 bh0 = *(const half8*)&w2hi[(ch * 32 + c) * RS2 + kb];
            half8 bl0 = *(const half8*)&w2lo[(ch * 32 + c) * RS2 + kb];
            half8 bh1 = *(const half8*)&w2hi[(ch * 32 + 16 + c) * RS2 + kb];
            half8 bl1 = *(const half8*)&w2lo[(ch * 32 + 16 + c) * RS2 + kb];
            acc0 = __builtin_amdgcn_mfma_f32_16x16x32_f16(a, bh0, acc0, 0, 0, 0);
            acc0 = __builtin_amdgcn_mfma_f32_16x16x32_f16(a, bl0, acc0, 0, 0, 0);
            acc1 = __builtin_amdgcn_mfma_f32_16x16x32_f16(a, bh1, acc1, 0, 0, 0);
            acc1 = __builtin_amdgcn_mfma_f32_16x16x32_f16(a, bl1, acc1, 0, 0, 0);
        }
        const int rowb = (bkt * 256 + half * 128) + r * 16 + q * 4;
#pragma unroll
        for (int rr = 0; rr < 4; ++rr) {
            if (rowb + rr < N_NODES) {
                // col-split store: both cols (ch*32+c, ch*32+16+c) live in
                // half ch at offsets c, c+16.
                _Float16* op = outB + (size_t)ch * WSPLIT
                             + (size_t)(rowb + rr) * HHALF + c;
                op[0]  = (_Float16)acc0[rr];
                op[16] = (_Float16)acc1[rr];
            }
        }
    }
}

// ---------------- agg2 (group-per-node, shfl payloads, 2 column passes) -----
__global__ __launch_bounds__(256) void agg2_k(const _Float16* __restrict__ Wh,
                                              const int* __restrict__ off,
                                              const unsigned int* __restrict__ es,
                                              float* __restrict__ out) {
    const int tid = threadIdx.x;
    const int lane = tid & 63;
    const int wid = tid >> 6;
    const int g = lane >> 3, p = lane & 7;
    const int node = blockIdx.x * 32 + wid * 8 + g;
    const bool valid = node < N_NODES;
    int beg = 0, end = 0;
    if (valid) {
        const int o = (node >> 8) * 257 + (node & 255);
        beg = off[o];
        end = off[o + 1];
    }
    const int deg = end - beg;

    unsigned int pld[5];
#pragma unroll
    for (int c = 0; c < 5; ++c) {
        int e = beg + c * 8 + p;
        pld[c] = (e < end) ? es[e] : 0u;
    }

    int mdeg = deg;
#pragma unroll
    for (int mask = 8; mask <= 32; mask <<= 1)
        mdeg = max(mdeg, __shfl_xor(mdeg, mask));

    const float inv = 1.0f / fmaxf((float)deg, 1.0f);

#pragma unroll
    for (int h = 0; h < 2; ++h) {
        const _Float16* Wp = Wh + (size_t)h * WSPLIT;
        float acc[4] = {0, 0, 0, 0};
#pragma unroll
        for (int c = 0; c < 5; ++c) {
            if (c * 8 >= mdeg) break;
#pragma unroll
            for (int s = 0; s < 8; ++s) {
                const unsigned int pe = __shfl(pld[c], (g << 3) | s);
                const bool act = beg + c * 8 + s < end;
                const int srow = act ? (int)(pe & 0xffff) : 0;   // row 0: L1-hot
                const float w = act
                    ? __half2float(__ushort_as_half((unsigned short)(pe >> 16)))
                    : 0.0f;
                half4 row = *(const half4*)(Wp + (size_t)srow * HHALF + p * 4);
#pragma unroll
                for (int j = 0; j < 4; ++j)
                    acc[j] = fmaf((float)row[j], w, acc[j]);
            }
        }
        for (int e = beg + 40; e < end; ++e) {    // rare tail (P ~ 8e-4)
            const unsigned int pe = es[e];
            const float w =
                __half2float(__ushort_as_half((unsigned short)(pe >> 16)));
            half4 row = *(const half4*)(Wp + (size_t)(pe & 0xffff) * HHALF
                                        + p * 4);
#pragma unroll
            for (int j = 0; j < 4; ++j)
                acc[j] = fmaf((float)row[j], w, acc[j]);
        }

        if (valid) {
            float4* op = (float4*)(out + (size_t)node * HID + h * HHALF + p * 4);
            op[0] = make_float4(acc[0] * inv, acc[1] * inv,
                                acc[2] * inv, acc[3] * inv);
        }
    }
}

extern "C" void kernel_launch(void* const* d_in, const int* in_sizes, int n_in,
                              void* d_out, int out_size, void* d_ws, size_t ws_size,
                              hipStream_t stream) {
    const float* x  = (const float*)d_in[0];
    const float* ew = (const float*)d_in[1];
    const float* W1 = (const float*)d_in[2];
    const float* b1 = (const float*)d_in[3];
    const float* W2 = (const float*)d_in[4];
    const float* b2 = (const float*)d_in[5];
    const int* src  = (const int*)d_in[6];
    const int* dst  = (const int*)d_in[7];
    float* out = (float*)d_out;

    const int NH = N_NODES * HID;
    const int ES = NBC * SLOTC;                             // 1,304,576

    // ws layout (~32 MB):
    // gcur | off(196*257+1) | esort u32 | epack int2 | bufA (Wh1) | bufB (Wh2)
    int* gcur = (int*)d_ws;                                 // 196 (+pad)
    int* off  = gcur + 200;                                 // 50373 (+pad)
    unsigned int* esort = (unsigned int*)(off + 50376);     // ES u32 (5.2 MB)
    int2* epack = (int2*)(esort + ES);                      // ES int2 (10.4 MB)
    _Float16* bufA = (_Float16*)(epack + ES);               // Wh1 split (6.4 MB)
    _Float16* bufB = bufA + NH;                             // Wh2 split (6.4 MB)

    const int agg2Blocks = (N_NODES + 31) / 32;             // 1563

    hipMemsetAsync(gcur, 0, NBC * sizeof(int), stream);

    // fill + gemm1 fused (independent inputs)
    fill_gemm1<<<FILL_BLOCKS + GEMM_BLOCKS, 1024, 0, stream>>>(
        src, dst, ew, gcur, epack, x, W1, b1, bufA);

    // sort + agg1 + gemm2 fused (block = half-bucket) -> esort/off + Wh2
    sort_agg1_gemm2<<<NBC * 2, 1024, 0, stream>>>(
        gcur, epack, bufA, W2, b2, esort, off, bufB);

    // final aggregation
    agg2_k<<<agg2Blocks, 256, 0, stream>>>(bufB, off, esort, out);
}